// Round 1
// baseline (1232.899 us; speedup 1.0000x reference)
//
#include <hip/hip_runtime.h>
#include <cstdint>
#include <cstddef>

#define B_    8192
#define N_    8
#define OBS_  128
#define HID_  128
#define H_    32
#define G3_   96
#define A_    14
#define QSIZE (B_*N_*A_)

#define TPB   256
#define GRIDX 32

// ---------------- kernel 1 (own path) LDS layout (float offsets) -------------
#define K1_W1   0        // [128][128]
#define K1_W2   16384    // [128][32]
#define K1_WIH  20480    // [32][96]
#define K1_B1   23552    // [128]
#define K1_B2   23680    // [32]
#define K1_BIH  23712    // [96]
#define K1_BHH  23808    // [96]
#define K1_IN   23904    // [64][132] obs -> h1 -> gx as [64][100]
#define K1_XH   32352    // [64][66]: cols0..31 = x, cols32..63 = hidden
#define K1_NF   36576
#define K1_BYTES (K1_NF*4)

// ---------------- kernel 2 (comm path) LDS layout ----------------------------
#define K2_WC1  0        // [128][128]
#define K2_WC2  16384    // [128][32]
#define K2_WIHC 20480    // [32][96]
#define K2_WQ   23552    // [64][14]
#define K2_BC1  24448    // [128]
#define K2_BC2  24576    // [32]
#define K2_BIHC 24608    // [96]
#define K2_BHHC 24704    // [96]
#define K2_BQ   24800    // [16]
#define K2_IN   24816    // [64][132] comm -> h1 -> g as [64][100]
#define K2_H2   33264    // [64][36]
#define K2_HID  35568    // [8][32]
#define K2_GHC  35824    // [8][96]
#define K2_CV   36592    // [8][32]
#define K2_NF   36848
#define K2_BYTES (K2_NF*4)

__device__ __forceinline__ float sigf(float x) { return 1.0f/(1.0f + __expf(-x)); }
__device__ __forceinline__ float tanh_fast(float x) {
  x = fminf(15.0f, fmaxf(-15.0f, x));
  const float e = __expf(2.0f*x);
  return (e - 1.0f)/(e + 1.0f);
}
__device__ __forceinline__ float relu_(float x){ return fmaxf(x, 0.0f); }

// ============================================================================
// Kernel 1: own-feature MLP + own GRU -> next_h (written to d_out tail)
// ============================================================================
__global__ void __launch_bounds__(TPB)
qnet_own(const float* __restrict__ obs, const float* __restrict__ hidden,
         const float* __restrict__ W1, const float* __restrict__ b1,
         const float* __restrict__ W2, const float* __restrict__ b2,
         const float* __restrict__ Wih, const float* __restrict__ Whh,
         const float* __restrict__ bih, const float* __restrict__ bhh,
         float* __restrict__ nh_out)
{
  extern __shared__ float sm[];
  const int tid = threadIdx.x;
  const int n   = blockIdx.y;
  const int cg  = tid & 15;    // 16 col-groups
  const int rg  = tid >> 4;    // 16 row-groups x 4 rows

  { // ---- stage per-agent weights (once per block) ----
    const float4* w1g = (const float4*)(W1 + (size_t)n*OBS_*HID_);
    float4* w1s = (float4*)(sm + K1_W1);
    for (int l = tid; l < 4096; l += TPB) w1s[l] = w1g[l];
    const float4* w2g = (const float4*)(W2 + (size_t)n*HID_*H_);
    float4* w2s = (float4*)(sm + K1_W2);
    for (int l = tid; l < 1024; l += TPB) w2s[l] = w2g[l];
    const float4* wig = (const float4*)(Wih + (size_t)n*H_*G3_);
    float4* wis = (float4*)(sm + K1_WIH);
    for (int l = tid; l < 768; l += TPB) wis[l] = wig[l];
    if (tid < 32) ((float4*)(sm+K1_B1))[tid] = ((const float4*)(b1 + n*HID_))[tid];
    if (tid >= 64 && tid < 72)   ((float4*)(sm+K1_B2 ))[tid-64 ] = ((const float4*)(b2  + n*H_ ))[tid-64 ];
    if (tid >= 96 && tid < 120)  ((float4*)(sm+K1_BIH))[tid-96 ] = ((const float4*)(bih + n*G3_))[tid-96 ];
    if (tid >= 128 && tid < 152) ((float4*)(sm+K1_BHH))[tid-128] = ((const float4*)(bhh + n*G3_))[tid-128];
  }
  __syncthreads();

  for (int t = 0; t < B_/(64*GRIDX); ++t) {
    const int b0 = (t*GRIDX + (int)blockIdx.x) * 64;

    // ---- stage obs -> IN[64][132]; hidden -> XH[r][32..63] ----
    for (int l = tid; l < 2048; l += TPB) {
      const int r = l >> 5, c = l & 31;
      const float4 v = ((const float4*)(obs + ((size_t)(b0+r)*N_ + n)*OBS_))[c];
      *(float4*)(sm + K1_IN + r*132 + 4*c) = v;
    }
    for (int l = tid; l < 1024; l += TPB) {
      const int r = l >> 4, c = l & 15;
      const float2 v = ((const float2*)(hidden + ((size_t)(b0+r)*N_ + n)*H_))[c];
      *(float2*)(sm + K1_XH + r*66 + 32 + 2*c) = v;
    }
    __syncthreads();

    // ---- L1: h1 = relu(obs*W1 + b1); rows 4rg+q, cols {4cg..}+{64+4cg..} ----
    float acc[4][8];
    {
      const float4 bA = *(const float4*)(sm + K1_B1 + 4*cg);
      const float4 bB = *(const float4*)(sm + K1_B1 + 64 + 4*cg);
#pragma unroll
      for (int q = 0; q < 4; ++q) {
        acc[q][0]=bA.x; acc[q][1]=bA.y; acc[q][2]=bA.z; acc[q][3]=bA.w;
        acc[q][4]=bB.x; acc[q][5]=bB.y; acc[q][6]=bB.z; acc[q][7]=bB.w;
      }
      const float* wb = sm + K1_W1 + 4*cg;
#pragma unroll 4
      for (int k = 0; k < 128; ++k) {
        const float4 w0 = *(const float4*)(wb + k*128);
        const float4 w1 = *(const float4*)(wb + k*128 + 64);
#pragma unroll
        for (int q = 0; q < 4; ++q) {
          const float a = sm[K1_IN + (4*rg+q)*132 + k];
          acc[q][0] = fmaf(a, w0.x, acc[q][0]);
          acc[q][1] = fmaf(a, w0.y, acc[q][1]);
          acc[q][2] = fmaf(a, w0.z, acc[q][2]);
          acc[q][3] = fmaf(a, w0.w, acc[q][3]);
          acc[q][4] = fmaf(a, w1.x, acc[q][4]);
          acc[q][5] = fmaf(a, w1.y, acc[q][5]);
          acc[q][6] = fmaf(a, w1.z, acc[q][6]);
          acc[q][7] = fmaf(a, w1.w, acc[q][7]);
        }
      }
    }
    __syncthreads();            // everyone done reading IN
#pragma unroll
    for (int q = 0; q < 4; ++q) {
      *(float4*)(sm + K1_IN + (4*rg+q)*132 + 4*cg) =
        make_float4(relu_(acc[q][0]),relu_(acc[q][1]),relu_(acc[q][2]),relu_(acc[q][3]));
      *(float4*)(sm + K1_IN + (4*rg+q)*132 + 64 + 4*cg) =
        make_float4(relu_(acc[q][4]),relu_(acc[q][5]),relu_(acc[q][6]),relu_(acc[q][7]));
    }
    __syncthreads();            // h1 visible

    // ---- L2: x = relu(h1*W2 + b2); cols {2cg,2cg+1} -> XH cols 0..31 ----
    {
      float a2[4][2];
      const float2 b2v = *(const float2*)(sm + K1_B2 + 2*cg);
#pragma unroll
      for (int q = 0; q < 4; ++q) { a2[q][0]=b2v.x; a2[q][1]=b2v.y; }
      const float* wb = sm + K1_W2 + 2*cg;
#pragma unroll 4
      for (int k = 0; k < 128; ++k) {
        const float2 w = *(const float2*)(wb + k*32);
#pragma unroll
        for (int q = 0; q < 4; ++q) {
          const float a = sm[K1_IN + (4*rg+q)*132 + k];
          a2[q][0] = fmaf(a, w.x, a2[q][0]);
          a2[q][1] = fmaf(a, w.y, a2[q][1]);
        }
      }
#pragma unroll
      for (int q = 0; q < 4; ++q)
        *(float2*)(sm + K1_XH + (4*rg+q)*66 + 2*cg) =
          make_float2(relu_(a2[q][0]), relu_(a2[q][1]));
    }
    __syncthreads();            // x visible

    // ---- gx = x*Wih + bih -> IN as [64][100], cols 6cg..6cg+5 ----
    {
      float ag[4][6];
#pragma unroll
      for (int q = 0; q < 4; ++q)
#pragma unroll
        for (int c = 0; c < 6; ++c) ag[q][c] = sm[K1_BIH + 6*cg + c];
      const float* wb = sm + K1_WIH + 6*cg;
#pragma unroll 2
      for (int k = 0; k < 32; ++k) {
        const float2 wA = *(const float2*)(wb + k*96);
        const float2 wB = *(const float2*)(wb + k*96 + 2);
        const float2 wC = *(const float2*)(wb + k*96 + 4);
#pragma unroll
        for (int q = 0; q < 4; ++q) {
          const float a = sm[K1_XH + (4*rg+q)*66 + k];
          ag[q][0]=fmaf(a,wA.x,ag[q][0]); ag[q][1]=fmaf(a,wA.y,ag[q][1]);
          ag[q][2]=fmaf(a,wB.x,ag[q][2]); ag[q][3]=fmaf(a,wB.y,ag[q][3]);
          ag[q][4]=fmaf(a,wC.x,ag[q][4]); ag[q][5]=fmaf(a,wC.y,ag[q][5]);
        }
      }
#pragma unroll
      for (int q = 0; q < 4; ++q) {
        *(float2*)(sm + K1_IN + (4*rg+q)*100 + 6*cg)     = make_float2(ag[q][0], ag[q][1]);
        *(float2*)(sm + K1_IN + (4*rg+q)*100 + 6*cg + 2) = make_float2(ag[q][2], ag[q][3]);
        *(float2*)(sm + K1_IN + (4*rg+q)*100 + 6*cg + 4) = make_float2(ag[q][4], ag[q][5]);
      }
    }

    // ---- gh kept in registers (n-gate needs hn separate!): cols {2cg,2cg+1}
    float gh[4][6];
#pragma unroll
    for (int q = 0; q < 4; ++q) {
      gh[q][0]=sm[K1_BHH + 2*cg];      gh[q][1]=sm[K1_BHH + 2*cg + 1];
      gh[q][2]=sm[K1_BHH + 32 + 2*cg]; gh[q][3]=sm[K1_BHH + 32 + 2*cg + 1];
      gh[q][4]=sm[K1_BHH + 64 + 2*cg]; gh[q][5]=sm[K1_BHH + 64 + 2*cg + 1];
    }
    {
      const float* whg = Whh + (size_t)n*H_*G3_ + 2*cg;   // global, L1/L2-hot (12 KB)
#pragma unroll 2
      for (int k = 0; k < 32; ++k) {
        const float2 wr = *(const float2*)(whg + k*96);
        const float2 wz = *(const float2*)(whg + k*96 + 32);
        const float2 wn = *(const float2*)(whg + k*96 + 64);
#pragma unroll
        for (int q = 0; q < 4; ++q) {
          const float a = sm[K1_XH + (4*rg+q)*66 + 32 + k];
          gh[q][0]=fmaf(a,wr.x,gh[q][0]); gh[q][1]=fmaf(a,wr.y,gh[q][1]);
          gh[q][2]=fmaf(a,wz.x,gh[q][2]); gh[q][3]=fmaf(a,wz.y,gh[q][3]);
          gh[q][4]=fmaf(a,wn.x,gh[q][4]); gh[q][5]=fmaf(a,wn.y,gh[q][5]);
        }
      }
    }
    __syncthreads();            // gx visible

    // ---- GRU; next_h -> global ----
#pragma unroll
    for (int q = 0; q < 4; ++q) {
      const float* g = sm + K1_IN + (4*rg+q)*100;
      float o[2];
#pragma unroll
      for (int c = 0; c < 2; ++c) {
        const int h = 2*cg + c;
        const float r  = sigf(g[h]    + gh[q][0+c]);
        const float z  = sigf(g[32+h] + gh[q][2+c]);
        const float nn = tanh_fast(fmaf(r, gh[q][4+c], g[64+h]));
        const float hp = sm[K1_XH + (4*rg+q)*66 + 32 + h];
        o[c] = fmaf(z, hp - nn, nn);  // (1-z)*n + z*h
      }
      *(float2*)(nh_out + ((size_t)(b0 + 4*rg+q)*N_ + n)*H_ + 2*cg) = make_float2(o[0], o[1]);
    }
    __syncthreads();            // protect IN/XH before next stage
  }
}

// ============================================================================
// Kernel 2: comm MLP + comm GRU + masked mean + Q head
// ============================================================================
__global__ void __launch_bounds__(TPB)
qnet_comm(const float* __restrict__ comm, const float* __restrict__ hidden,
          const float* __restrict__ Wc1, const float* __restrict__ bc1,
          const float* __restrict__ Wc2, const float* __restrict__ bc2,
          const float* __restrict__ Wihc, const float* __restrict__ bihc,
          const float* __restrict__ bhhc, const float* __restrict__ Whhc,
          const float* __restrict__ Wq, const float* __restrict__ bq,
          const float* __restrict__ nh_in, float* __restrict__ q_out)
{
  extern __shared__ float sm[];
  const int tid = threadIdx.x;
  const int i   = blockIdx.y;
  const int cg  = tid & 15;
  const int rg  = tid >> 4;

  { // ---- stage per-agent weights ----
    const float4* g1 = (const float4*)(Wc1 + (size_t)i*OBS_*HID_);
    float4* s1 = (float4*)(sm + K2_WC1);
    for (int l = tid; l < 4096; l += TPB) s1[l] = g1[l];
    const float4* g2 = (const float4*)(Wc2 + (size_t)i*HID_*H_);
    float4* s2 = (float4*)(sm + K2_WC2);
    for (int l = tid; l < 1024; l += TPB) s2[l] = g2[l];
    const float4* g3 = (const float4*)(Wihc + (size_t)i*H_*G3_);
    float4* s3 = (float4*)(sm + K2_WIHC);
    for (int l = tid; l < 768; l += TPB) s3[l] = g3[l];
    const float4* g4 = (const float4*)(Wq + (size_t)i*2*H_*A_);
    float4* s4 = (float4*)(sm + K2_WQ);
    for (int l = tid; l < 224; l += TPB) s4[l] = g4[l];
    if (tid < 32) ((float4*)(sm+K2_BC1))[tid] = ((const float4*)(bc1 + i*OBS_))[tid];
    if (tid >= 64 && tid < 72)   ((float4*)(sm+K2_BC2 ))[tid-64 ] = ((const float4*)(bc2  + i*H_ ))[tid-64 ];
    if (tid >= 96 && tid < 120)  ((float4*)(sm+K2_BIHC))[tid-96 ] = ((const float4*)(bihc + i*G3_))[tid-96 ];
    if (tid >= 128 && tid < 152) ((float4*)(sm+K2_BHHC))[tid-128] = ((const float4*)(bhhc + i*G3_))[tid-128];
    if (tid >= 160 && tid < 174) sm[K2_BQ + tid-160] = bq[i*A_ + tid-160];
  }
  __syncthreads();

  for (int t = 0; t < B_/(8*GRIDX); ++t) {
    const int b0 = (t*GRIDX + (int)blockIdx.x) * 8;  // 8 b's; 64 rows = 8b x 8j

    // ---- stage comm tile + hidden ----
    for (int l = tid; l < 2048; l += TPB) {
      const int r = l >> 5, c = l & 31;       // r = bb*8 + j
      const size_t grow = (size_t)(b0 + (r>>3))*64 + (size_t)i*8 + (r&7);
      const float4 v = ((const float4*)(comm + grow*OBS_))[c];
      *(float4*)(sm + K2_IN + r*132 + 4*c) = v;
    }
    if (tid < 64) {
      const int bb = tid >> 3, c = tid & 7;
      const float4 v = ((const float4*)(hidden + ((size_t)(b0+bb)*N_ + i)*H_))[c];
      *(float4*)(sm + K2_HID + bb*32 + 4*c) = v;
    }
    __syncthreads();

    // ---- L1: h1 = relu(comm*Wc1 + bc1) ----
    float acc[4][8];
    {
      const float4 bA = *(const float4*)(sm + K2_BC1 + 4*cg);
      const float4 bB = *(const float4*)(sm + K2_BC1 + 64 + 4*cg);
#pragma unroll
      for (int q = 0; q < 4; ++q) {
        acc[q][0]=bA.x; acc[q][1]=bA.y; acc[q][2]=bA.z; acc[q][3]=bA.w;
        acc[q][4]=bB.x; acc[q][5]=bB.y; acc[q][6]=bB.z; acc[q][7]=bB.w;
      }
      const float* wb = sm + K2_WC1 + 4*cg;
#pragma unroll 4
      for (int k = 0; k < 128; ++k) {
        const float4 w0 = *(const float4*)(wb + k*128);
        const float4 w1 = *(const float4*)(wb + k*128 + 64);
#pragma unroll
        for (int q = 0; q < 4; ++q) {
          const float a = sm[K2_IN + (4*rg+q)*132 + k];
          acc[q][0] = fmaf(a, w0.x, acc[q][0]);
          acc[q][1] = fmaf(a, w0.y, acc[q][1]);
          acc[q][2] = fmaf(a, w0.z, acc[q][2]);
          acc[q][3] = fmaf(a, w0.w, acc[q][3]);
          acc[q][4] = fmaf(a, w1.x, acc[q][4]);
          acc[q][5] = fmaf(a, w1.y, acc[q][5]);
          acc[q][6] = fmaf(a, w1.z, acc[q][6]);
          acc[q][7] = fmaf(a, w1.w, acc[q][7]);
        }
      }
    }
    __syncthreads();
#pragma unroll
    for (int q = 0; q < 4; ++q) {
      *(float4*)(sm + K2_IN + (4*rg+q)*132 + 4*cg) =
        make_float4(relu_(acc[q][0]),relu_(acc[q][1]),relu_(acc[q][2]),relu_(acc[q][3]));
      *(float4*)(sm + K2_IN + (4*rg+q)*132 + 64 + 4*cg) =
        make_float4(relu_(acc[q][4]),relu_(acc[q][5]),relu_(acc[q][6]),relu_(acc[q][7]));
    }
    __syncthreads();

    // ---- L2: h2 = relu(h1*Wc2 + bc2) -> H2[64][36] ----
    {
      float a2[4][2];
      const float2 b2v = *(const float2*)(sm + K2_BC2 + 2*cg);
#pragma unroll
      for (int q = 0; q < 4; ++q) { a2[q][0]=b2v.x; a2[q][1]=b2v.y; }
      const float* wb = sm + K2_WC2 + 2*cg;
#pragma unroll 4
      for (int k = 0; k < 128; ++k) {
        const float2 w = *(const float2*)(wb + k*32);
#pragma unroll
        for (int q = 0; q < 4; ++q) {
          const float a = sm[K2_IN + (4*rg+q)*132 + k];
          a2[q][0] = fmaf(a, w.x, a2[q][0]);
          a2[q][1] = fmaf(a, w.y, a2[q][1]);
        }
      }
#pragma unroll
      for (int q = 0; q < 4; ++q)
        *(float2*)(sm + K2_H2 + (4*rg+q)*36 + 2*cg) =
          make_float2(relu_(a2[q][0]), relu_(a2[q][1]));
    }
    __syncthreads();

    // ---- gates: gxc = h2*Wihc + bihc -> IN as [64][100] ----
    {
      float ag[4][6];
#pragma unroll
      for (int q = 0; q < 4; ++q)
#pragma unroll
        for (int c = 0; c < 6; ++c) ag[q][c] = sm[K2_BIHC + 6*cg + c];
      const float* wb = sm + K2_WIHC + 6*cg;
#pragma unroll 2
      for (int k = 0; k < 32; ++k) {
        const float2 wA = *(const float2*)(wb + k*96);
        const float2 wB = *(const float2*)(wb + k*96 + 2);
        const float2 wC = *(const float2*)(wb + k*96 + 4);
#pragma unroll
        for (int q = 0; q < 4; ++q) {
          const float a = sm[K2_H2 + (4*rg+q)*36 + k];
          ag[q][0]=fmaf(a,wA.x,ag[q][0]); ag[q][1]=fmaf(a,wA.y,ag[q][1]);
          ag[q][2]=fmaf(a,wB.x,ag[q][2]); ag[q][3]=fmaf(a,wB.y,ag[q][3]);
          ag[q][4]=fmaf(a,wC.x,ag[q][4]); ag[q][5]=fmaf(a,wC.y,ag[q][5]);
        }
      }
#pragma unroll
      for (int q = 0; q < 4; ++q) {
        *(float2*)(sm + K2_IN + (4*rg+q)*100 + 6*cg)     = make_float2(ag[q][0], ag[q][1]);
        *(float2*)(sm + K2_IN + (4*rg+q)*100 + 6*cg + 2) = make_float2(ag[q][2], ag[q][3]);
        *(float2*)(sm + K2_IN + (4*rg+q)*100 + 6*cg + 4) = make_float2(ag[q][4], ag[q][5]);
      }
    }
    // ---- ghc = hidden*Whhc + bhhc (per (bb), shared over j) ----
    {
      const int bb = tid >> 5;
      const int g0 = 3*(tid & 31);
      float g3v[3] = { sm[K2_BHHC+g0], sm[K2_BHHC+g0+1], sm[K2_BHHC+g0+2] };
      const float* wh = Whhc + (size_t)i*H_*G3_ + g0;     // global, L1-hot (12 KB)
#pragma unroll 4
      for (int k = 0; k < 32; ++k) {
        const float hv = sm[K2_HID + bb*32 + k];
        g3v[0] = fmaf(hv, wh[k*96+0], g3v[0]);
        g3v[1] = fmaf(hv, wh[k*96+1], g3v[1]);
        g3v[2] = fmaf(hv, wh[k*96+2], g3v[2]);
      }
      sm[K2_GHC + bb*96 + g0]   = g3v[0];
      sm[K2_GHC + bb*96 + g0+1] = g3v[1];
      sm[K2_GHC + bb*96 + g0+2] = g3v[2];
    }
    __syncthreads();

    // ---- comm GRU + masked mean over j != i ----
    {
      const int bb = tid >> 5, h = tid & 31;
      const float hp = sm[K2_HID + bb*32 + h];
      const float hr = sm[K2_GHC + bb*96 + h];
      const float hz = sm[K2_GHC + bb*96 + 32 + h];
      const float hn = sm[K2_GHC + bb*96 + 64 + h];
      float s = 0.0f;
#pragma unroll
      for (int j = 0; j < 8; ++j) {
        const float* g = sm + K2_IN + (bb*8 + j)*100;
        const float r  = sigf(g[h]    + hr);
        const float z  = sigf(g[32+h] + hz);
        const float nn = tanh_fast(fmaf(r, hn, g[64+h]));
        const float hc = fmaf(z, hp - nn, nn);
        s += (j == i) ? 0.0f : hc;
      }
      sm[K2_CV + tid] = s * (1.0f/7.0f);
    }
    __syncthreads();

    // ---- Q head: q = [next_h, cv] * Wq + bq ----
    if (tid < 112) {
      const int bb = tid / 14, a = tid - bb*14;
      const float* nh = nh_in + ((size_t)(b0+bb)*N_ + i)*H_;
      float qv = sm[K2_BQ + a];
#pragma unroll 4
      for (int h = 0; h < 32; ++h)
        qv = fmaf(nh[h], sm[K2_WQ + h*A_ + a], qv);
#pragma unroll 4
      for (int h = 0; h < 32; ++h)
        qv = fmaf(sm[K2_CV + bb*32 + h], sm[K2_WQ + (32+h)*A_ + a], qv);
      q_out[((size_t)(b0+bb)*N_ + i)*A_ + a] = qv;
    }
    // no trailing barrier needed: next stage writes IN/HID (readers finished at
    // the post-GRU barrier); Q reads only CV/WQ/BQ/global, untouched by staging.
  }
}

// ============================================================================
extern "C" void kernel_launch(void* const* d_in, const int* in_sizes, int n_in,
                              void* d_out, int out_size, void* d_ws, size_t ws_size,
                              hipStream_t stream) {
  const float* obs    = (const float*)d_in[0];
  const float* hidden = (const float*)d_in[1];
  const float* comm   = (const float*)d_in[2];
  const float* W1  = (const float*)d_in[3];  const float* b1  = (const float*)d_in[4];
  const float* W2  = (const float*)d_in[5];  const float* b2  = (const float*)d_in[6];
  const float* Wc1 = (const float*)d_in[7];  const float* bc1 = (const float*)d_in[8];
  const float* Wc2 = (const float*)d_in[9];  const float* bc2 = (const float*)d_in[10];
  const float* Wih = (const float*)d_in[11]; const float* Whh = (const float*)d_in[12];
  const float* bih = (const float*)d_in[13]; const float* bhh = (const float*)d_in[14];
  const float* Wihc= (const float*)d_in[15]; const float* Whhc= (const float*)d_in[16];
  const float* bihc= (const float*)d_in[17]; const float* bhhc= (const float*)d_in[18];
  const float* Wq  = (const float*)d_in[19]; const float* bq  = (const float*)d_in[20];

  float* q_out  = (float*)d_out;
  float* nh_out = q_out + QSIZE;

  // Dynamic LDS > 64 KB: opt in every call (idempotent; host-side, capture-safe).
  (void)hipFuncSetAttribute(reinterpret_cast<const void*>(qnet_own),
                            hipFuncAttributeMaxDynamicSharedMemorySize, K1_BYTES);
  (void)hipFuncSetAttribute(reinterpret_cast<const void*>(qnet_comm),
                            hipFuncAttributeMaxDynamicSharedMemorySize, K2_BYTES);

  dim3 blk(TPB);
  qnet_own <<<dim3(GRIDX, N_), blk, K1_BYTES, stream>>>(
      obs, hidden, W1, b1, W2, b2, Wih, Whh, bih, bhh, nh_out);
  qnet_comm<<<dim3(GRIDX, N_), blk, K2_BYTES, stream>>>(
      comm, hidden, Wc1, bc1, Wc2, bc2, Wihc, bihc, bhhc, Whhc, Wq, bq,
      nh_out, q_out);
}